// Round 3
// baseline (415.555 us; speedup 1.0000x reference)
//
#include <hip/hip_runtime.h>
#include <math.h>

#define EPS_GS 1e-8f
#define RAD2DEG 57.29577951308232f
#define PI_F 3.14159265358979f
#define ROT_PER_BLOCK 512   // rotations per block (2 per thread)

__device__ __forceinline__ float clip10(float x) {
    x = x < -10.f ? -10.f : x;
    x = x >  10.f ?  10.f : x;
    return x;
}

__device__ __forceinline__ float fsqrt(float x) { return __builtin_amdgcn_sqrtf(x); }
__device__ __forceinline__ float frcp(float x)  { return __builtin_amdgcn_rcpf(x); }

// Abramowitz-Stegun 4.4.45: max error 6.76e-5 rad
__device__ __forceinline__ float fast_acos(float x) {
    float ax = fabsf(x);
    float p = fmaf(ax, -0.0187293f, 0.0742610f);
    p = fmaf(ax, p, -0.2121144f);
    p = fmaf(ax, p, 1.5707288f);
    float pos = fsqrt(1.f - ax) * p;
    return x >= 0.f ? pos : PI_F - pos;
}

// v: 3x3 row-major (clipped). R: rotation with columns e1,e2,e3 (det-fixed).
__device__ __forceinline__ void gs_rotmat(const float* v, float* R) {
    float c0x = v[0], c0y = v[3], c0z = v[6];
    float c1x = v[1], c1y = v[4], c1z = v[7];
    float c2x = v[2], c2y = v[5], c2z = v[8];

    float s1 = fmaf(c0x, c0x, fmaf(c0y, c0y, c0z*c0z));
    float inv1 = frcp(fsqrt(s1) + EPS_GS);
    float e1x = c0x*inv1, e1y = c0y*inv1, e1z = c0z*inv1;

    float d = fmaf(e1x, c1x, fmaf(e1y, c1y, e1z*c1z));
    float u2x = fmaf(-d, e1x, c1x), u2y = fmaf(-d, e1y, c1y), u2z = fmaf(-d, e1z, c1z);
    float s2 = fmaf(u2x, u2x, fmaf(u2y, u2y, u2z*u2z));
    float inv2 = frcp(fsqrt(s2) + EPS_GS);
    float e2x = u2x*inv2, e2y = u2y*inv2, e2z = u2z*inv2;

    float d1 = fmaf(e1x, c2x, fmaf(e1y, c2y, e1z*c2z));
    float d2 = fmaf(e2x, c2x, fmaf(e2y, c2y, e2z*c2z));
    float u3x = fmaf(-d1, e1x, fmaf(-d2, e2x, c2x));
    float u3y = fmaf(-d1, e1y, fmaf(-d2, e2y, c2y));
    float u3z = fmaf(-d1, e1z, fmaf(-d2, e2z, c2z));
    float s3 = fmaf(u3x, u3x, fmaf(u3y, u3y, u3z*u3z));
    float inv3 = frcp(fsqrt(s3) + EPS_GS);
    float e3x = u3x*inv3, e3y = u3y*inv3, e3z = u3z*inv3;

    float cxx = e2y*e3z - e2z*e3y;
    float cxy = e2z*e3x - e2x*e3z;
    float cxz = e2x*e3y - e2y*e3x;
    float det = fmaf(e1x, cxx, fmaf(e1y, cxy, e1z*cxz));
    if (det < 0.f) { e3x = -e3x; e3y = -e3y; e3z = -e3z; }

    R[0] = e1x; R[1] = e2x; R[2] = e3x;
    R[3] = e1y; R[4] = e2y; R[5] = e3y;
    R[6] = e1z; R[7] = e2z; R[8] = e3z;
}

__device__ __forceinline__ void accum_rot(const float* pr, const float* tg,
                                          float& lt, float& lf) {
    float pc[9], tc[9];
    #pragma unroll
    for (int m = 0; m < 9; ++m) { pc[m] = clip10(pr[m]); tc[m] = clip10(tg[m]); }

    float Rp[9], Rt[9];
    gs_rotmat(pc, Rp);
    gs_rotmat(tc, Rt);

    float chord = 0.f, tr = 0.f;
    #pragma unroll
    for (int m = 0; m < 9; ++m) {
        float d = Rp[m] - Rt[m];
        chord = fmaf(d, d, chord);
        tr    = fmaf(Rp[m], Rt[m], tr);
    }

    const float trLo = -3.0f + 1e-6f, trHi = 3.0f - 1e-6f;
    tr = tr < trLo ? trLo : (tr > trHi ? trHi : tr);
    float ca = (tr - 1.f) * 0.5f;
    const float cLo = -1.0f + 1e-7f, cHi = 1.0f - 1e-7f;
    ca = ca < cLo ? cLo : (ca > cHi ? cHi : ca);
    float ang = fast_acos(ca) * RAD2DEG;
    if (ang != ang) ang = 180.f;

    float o = 0.f;
    #pragma unroll
    for (int i = 0; i < 3; ++i) {
        #pragma unroll
        for (int j = 0; j < 3; ++j) {
            float s = fmaf(pc[i], pc[j], fmaf(pc[3+i], pc[3+j], pc[6+i]*pc[6+j]));
            s -= (i == j) ? 1.f : 0.f;
            o = fmaf(s, s, o);
        }
    }

    float l2 = 0.f, fb = 0.f;
    #pragma unroll
    for (int m = 0; m < 9; ++m) {
        l2 = fmaf(pc[m], pc[m], l2);
        float d = pc[m] - tg[m];   // fallback uses UNclipped target
        fb = fmaf(d, d, fb);
    }

    lt += fmaf(0.1f, ang, chord) + fmaf(0.01f, o, (1e-4f/9.f)*l2);
    lf += fb;
}

__device__ __forceinline__ void block_reduce_atomic(float lt, float lf, double* acc) {
    #pragma unroll
    for (int off = 32; off > 0; off >>= 1) {
        lt += __shfl_down(lt, off, 64);
        lf += __shfl_down(lf, off, 64);
    }
    __shared__ float st[4], sf[4];
    const int lane = threadIdx.x & 63;
    const int wid  = threadIdx.x >> 6;
    if (lane == 0) { st[wid] = lt; sf[wid] = lf; }
    __syncthreads();
    if (threadIdx.x == 0) {
        int nw = (blockDim.x + 63) >> 6;
        float bt = 0.f, bf = 0.f;
        for (int w = 0; w < nw; ++w) { bt += st[w]; bf += sf[w]; }
        unsafeAtomicAdd(&acc[0], (double)bt);
        unsafeAtomicAdd(&acc[1], (double)bf);
    }
}

__global__ __launch_bounds__(256)
void rot_loss_lds(const float* __restrict__ pred, const float* __restrict__ targ,
                  double* __restrict__ acc) {
    __shared__ float sP[ROT_PER_BLOCK * 9];   // 18432 B
    __shared__ float sT[ROT_PER_BLOCK * 9];   // 18432 B

    const int tid  = threadIdx.x;
    const int wave = tid >> 6;
    const int lane = tid & 63;
    const size_t chunkByte = (size_t)blockIdx.x * (ROT_PER_BLOCK * 36);

    const char* gp = (const char*)pred + chunkByte;
    const char* gt = (const char*)targ + chunkByte;

    // 18 KB per input = 18 wave-chunks of 1 KB; fully coalesced, async to LDS.
    #pragma unroll
    for (int j = wave; j < 18; j += 4) {
        __builtin_amdgcn_global_load_lds(
            (const __attribute__((address_space(1))) unsigned int*)(gp + j*1024 + lane*16),
            (__attribute__((address_space(3))) unsigned int*)((char*)sP + j*1024),
            16, 0, 0);
    }
    #pragma unroll
    for (int j = wave; j < 18; j += 4) {
        __builtin_amdgcn_global_load_lds(
            (const __attribute__((address_space(1))) unsigned int*)(gt + j*1024 + lane*16),
            (__attribute__((address_space(3))) unsigned int*)((char*)sT + j*1024),
            16, 0, 0);
    }
    __syncthreads();  // drains vmcnt -> LDS valid

    float lt = 0.f, lf = 0.f;
    // stride-9-float LDS reads: lanes cycle all 32 banks -> free 2-way aliasing
    accum_rot(&sP[tid * 9],         &sT[tid * 9],         lt, lf);
    accum_rot(&sP[(tid + 256) * 9], &sT[(tid + 256) * 9], lt, lf);

    block_reduce_atomic(lt, lf, acc);
}

__global__ __launch_bounds__(256)
void rot_loss_tail(const float* __restrict__ pred, const float* __restrict__ targ,
                   double* __restrict__ acc, int start, int B) {
    int r = start + blockIdx.x * blockDim.x + threadIdx.x;
    float lt = 0.f, lf = 0.f;
    if (r < B) {
        float a[9], b[9];
        for (int m = 0; m < 9; ++m) { a[m] = pred[(size_t)r*9 + m]; b[m] = targ[(size_t)r*9 + m]; }
        accum_rot(a, b, lt, lf);
    }
    block_reduce_atomic(lt, lf, acc);
}

__global__ void finalize_kernel(const double* __restrict__ acc,
                                float* __restrict__ out, int B) {
    if (threadIdx.x == 0 && blockIdx.x == 0) {
        double total = acc[0] / (double)B;
        double fb    = acc[1] / (9.0 * (double)B);
        out[0] = isnan(total) ? (float)fb : (float)total;
    }
}

extern "C" void kernel_launch(void* const* d_in, const int* in_sizes, int n_in,
                              void* d_out, int out_size, void* d_ws, size_t ws_size,
                              hipStream_t stream) {
    const float* pred = (const float*)d_in[0];
    const float* targ = (const float*)d_in[1];
    const int n = in_sizes[0];
    const int B = n / 9;

    double* acc = (double*)d_ws;
    hipMemsetAsync(d_ws, 0, 2 * sizeof(double), stream);

    const int fullBlocks = B / ROT_PER_BLOCK;
    const int rem        = B - fullBlocks * ROT_PER_BLOCK;
    if (fullBlocks > 0)
        rot_loss_lds<<<fullBlocks, 256, 0, stream>>>(pred, targ, acc);
    if (rem > 0)
        rot_loss_tail<<<(rem + 255) / 256, 256, 0, stream>>>(
            pred, targ, acc, fullBlocks * ROT_PER_BLOCK, B);
    finalize_kernel<<<1, 64, 0, stream>>>(acc, (float*)d_out, B);
}

// Round 4
// 368.614 us; speedup vs baseline: 1.1273x; 1.1273x over previous
//
#include <hip/hip_runtime.h>
#include <math.h>

#define EPS_GS 1e-8f
#define RAD2DEG 57.29577951308232f
#define PI_F 3.14159265358979f
#define NBLOCKS 2048
#define NTHREADS 256

__device__ __forceinline__ float clip10(float x) {
    x = x < -10.f ? -10.f : x;
    x = x >  10.f ?  10.f : x;
    return x;
}

__device__ __forceinline__ float fsqrt(float x) { return __builtin_amdgcn_sqrtf(x); }
__device__ __forceinline__ float frcp(float x)  { return __builtin_amdgcn_rcpf(x); }

// Abramowitz-Stegun 4.4.45: max error 6.76e-5 rad
__device__ __forceinline__ float fast_acos(float x) {
    float ax = fabsf(x);
    float p = fmaf(ax, -0.0187293f, 0.0742610f);
    p = fmaf(ax, p, -0.2121144f);
    p = fmaf(ax, p, 1.5707288f);
    float pos = fsqrt(1.f - ax) * p;
    return x >= 0.f ? pos : PI_F - pos;
}

// v: 3x3 row-major (clipped). R: rotation with columns e1,e2,e3 (det-fixed).
__device__ __forceinline__ void gs_rotmat(const float* v, float* R) {
    float c0x = v[0], c0y = v[3], c0z = v[6];
    float c1x = v[1], c1y = v[4], c1z = v[7];
    float c2x = v[2], c2y = v[5], c2z = v[8];

    float s1 = fmaf(c0x, c0x, fmaf(c0y, c0y, c0z*c0z));
    float inv1 = frcp(fsqrt(s1) + EPS_GS);
    float e1x = c0x*inv1, e1y = c0y*inv1, e1z = c0z*inv1;

    float d = fmaf(e1x, c1x, fmaf(e1y, c1y, e1z*c1z));
    float u2x = fmaf(-d, e1x, c1x), u2y = fmaf(-d, e1y, c1y), u2z = fmaf(-d, e1z, c1z);
    float s2 = fmaf(u2x, u2x, fmaf(u2y, u2y, u2z*u2z));
    float inv2 = frcp(fsqrt(s2) + EPS_GS);
    float e2x = u2x*inv2, e2y = u2y*inv2, e2z = u2z*inv2;

    float d1 = fmaf(e1x, c2x, fmaf(e1y, c2y, e1z*c2z));
    float d2 = fmaf(e2x, c2x, fmaf(e2y, c2y, e2z*c2z));
    float u3x = fmaf(-d1, e1x, fmaf(-d2, e2x, c2x));
    float u3y = fmaf(-d1, e1y, fmaf(-d2, e2y, c2y));
    float u3z = fmaf(-d1, e1z, fmaf(-d2, e2z, c2z));
    float s3 = fmaf(u3x, u3x, fmaf(u3y, u3y, u3z*u3z));
    float inv3 = frcp(fsqrt(s3) + EPS_GS);
    float e3x = u3x*inv3, e3y = u3y*inv3, e3z = u3z*inv3;

    float cxx = e2y*e3z - e2z*e3y;
    float cxy = e2z*e3x - e2x*e3z;
    float cxz = e2x*e3y - e2y*e3x;
    float det = fmaf(e1x, cxx, fmaf(e1y, cxy, e1z*cxz));
    if (det < 0.f) { e3x = -e3x; e3y = -e3y; e3z = -e3z; }

    R[0] = e1x; R[1] = e2x; R[2] = e3x;
    R[3] = e1y; R[4] = e2y; R[5] = e3y;
    R[6] = e1z; R[7] = e2z; R[8] = e3z;
}

__device__ __forceinline__ void accum_rot(const float* pr, const float* tg,
                                          float& lt, float& lf) {
    float pc[9], tc[9];
    #pragma unroll
    for (int m = 0; m < 9; ++m) { pc[m] = clip10(pr[m]); tc[m] = clip10(tg[m]); }

    float Rp[9], Rt[9];
    gs_rotmat(pc, Rp);
    gs_rotmat(tc, Rt);

    float chord = 0.f, tr = 0.f;
    #pragma unroll
    for (int m = 0; m < 9; ++m) {
        float d = Rp[m] - Rt[m];
        chord = fmaf(d, d, chord);
        tr    = fmaf(Rp[m], Rt[m], tr);
    }

    const float trLo = -3.0f + 1e-6f, trHi = 3.0f - 1e-6f;
    tr = tr < trLo ? trLo : (tr > trHi ? trHi : tr);
    float ca = (tr - 1.f) * 0.5f;
    const float cLo = -1.0f + 1e-7f, cHi = 1.0f - 1e-7f;
    ca = ca < cLo ? cLo : (ca > cHi ? cHi : ca);
    float ang = fast_acos(ca) * RAD2DEG;
    if (ang != ang) ang = 180.f;

    float o = 0.f;
    #pragma unroll
    for (int i = 0; i < 3; ++i) {
        #pragma unroll
        for (int j = 0; j < 3; ++j) {
            float s = fmaf(pc[i], pc[j], fmaf(pc[3+i], pc[3+j], pc[6+i]*pc[6+j]));
            s -= (i == j) ? 1.f : 0.f;
            o = fmaf(s, s, o);
        }
    }

    float l2 = 0.f, fb = 0.f;
    #pragma unroll
    for (int m = 0; m < 9; ++m) {
        l2 = fmaf(pc[m], pc[m], l2);
        float d = pc[m] - tg[m];   // fallback uses UNclipped target
        fb = fmaf(d, d, fb);
    }

    lt += fmaf(0.1f, ang, chord) + fmaf(0.01f, o, (1e-4f/9.f)*l2);
    lf += fb;
}

__global__ __launch_bounds__(NTHREADS)
void rot_loss_kernel(const float* __restrict__ pred, const float* __restrict__ targ,
                     float2* __restrict__ partial, int B) {
    const int ngroups  = (B + 3) >> 2;           // groups of 4 rotations
    const int nthreads = gridDim.x * blockDim.x;

    float lt = 0.f, lf = 0.f;

    for (int g = blockIdx.x * blockDim.x + threadIdx.x; g < ngroups; g += nthreads) {
        const int base = g * 4;
        if (base + 3 < B) {
            const float4* p4 = reinterpret_cast<const float4*>(pred) + (size_t)g * 9;
            const float4* t4 = reinterpret_cast<const float4*>(targ) + (size_t)g * 9;
            float4 pv[9], tv[9];
            #pragma unroll
            for (int j = 0; j < 9; ++j) pv[j] = p4[j];
            #pragma unroll
            for (int j = 0; j < 9; ++j) tv[j] = t4[j];
            float a[36], b[36];
            #pragma unroll
            for (int j = 0; j < 9; ++j) {
                a[4*j+0] = pv[j].x; a[4*j+1] = pv[j].y; a[4*j+2] = pv[j].z; a[4*j+3] = pv[j].w;
                b[4*j+0] = tv[j].x; b[4*j+1] = tv[j].y; b[4*j+2] = tv[j].z; b[4*j+3] = tv[j].w;
            }
            #pragma unroll
            for (int k = 0; k < 4; ++k) accum_rot(&a[9*k], &b[9*k], lt, lf);
        } else {
            for (int r = base; r < B; ++r) {
                float a1[9], b1[9];
                for (int m = 0; m < 9; ++m) { a1[m] = pred[(size_t)r*9 + m]; b1[m] = targ[(size_t)r*9 + m]; }
                accum_rot(a1, b1, lt, lf);
            }
        }
    }

    // wave-64 reduce
    #pragma unroll
    for (int off = 32; off > 0; off >>= 1) {
        lt += __shfl_down(lt, off, 64);
        lf += __shfl_down(lf, off, 64);
    }
    __shared__ float st[4], sf[4];
    const int lane = threadIdx.x & 63;
    const int wid  = threadIdx.x >> 6;
    if (lane == 0) { st[wid] = lt; sf[wid] = lf; }
    __syncthreads();
    if (threadIdx.x == 0) {
        float bt = st[0] + st[1] + st[2] + st[3];
        float bf = sf[0] + sf[1] + sf[2] + sf[3];
        partial[blockIdx.x] = make_float2(bt, bf);   // plain store, unique slot: NO atomics
    }
}

__global__ __launch_bounds__(256)
void finalize_kernel(const float2* __restrict__ partial, int nparts,
                     float* __restrict__ out, int B) {
    double t = 0.0, f = 0.0;
    for (int i = threadIdx.x; i < nparts; i += 256) {
        float2 p = partial[i];
        t += (double)p.x;
        f += (double)p.y;
    }
    #pragma unroll
    for (int off = 32; off > 0; off >>= 1) {
        t += __shfl_down(t, off, 64);
        f += __shfl_down(f, off, 64);
    }
    __shared__ double st[4], sf[4];
    const int lane = threadIdx.x & 63;
    const int wid  = threadIdx.x >> 6;
    if (lane == 0) { st[wid] = t; sf[wid] = f; }
    __syncthreads();
    if (threadIdx.x == 0) {
        double total = (st[0] + st[1] + st[2] + st[3]) / (double)B;
        double fb    = (sf[0] + sf[1] + sf[2] + sf[3]) / (9.0 * (double)B);
        out[0] = isnan(total) ? (float)fb : (float)total;
    }
}

extern "C" void kernel_launch(void* const* d_in, const int* in_sizes, int n_in,
                              void* d_out, int out_size, void* d_ws, size_t ws_size,
                              hipStream_t stream) {
    const float* pred = (const float*)d_in[0];
    const float* targ = (const float*)d_in[1];
    const int n = in_sizes[0];
    const int B = n / 9;

    float2* partial = (float2*)d_ws;   // NBLOCKS slots, all overwritten each call

    rot_loss_kernel<<<NBLOCKS, NTHREADS, 0, stream>>>(pred, targ, partial, B);
    finalize_kernel<<<1, 256, 0, stream>>>(partial, NBLOCKS, (float*)d_out, B);
}